// Round 16
// baseline (1324.918 us; speedup 1.0000x reference)
//
#include <hip/hip_runtime.h>
#include <hip/hip_bf16.h>

// ---- problem constants ----
#define E_NUM 16
#define TOPK 4
#define H_DIM 2048
#define I_DIM 1408
#define IS_DIM 5632
#define M_TOK 4096

typedef __attribute__((ext_vector_type(8))) short short8;
typedef __attribute__((ext_vector_type(4))) float f32x4;

static __device__ __forceinline__ unsigned short f2bf(float f) {
    unsigned int u = __float_as_uint(f);
    unsigned int r = (u + 0x7FFFu + ((u >> 16) & 1u)) >> 16;
    return (unsigned short)r;
}

static __device__ __forceinline__ void gl16(const unsigned short* g, unsigned short* l) {
    __builtin_amdgcn_global_load_lds(
        (const __attribute__((address_space(1))) unsigned int*)g,
        (__attribute__((address_space(3))) unsigned int*)l, 16, 0, 0);
}

// ---------------- router: fp32 logits, softmax, top-4, shared gate ----------------
__global__ __launch_bounds__(256) void k_router(
    const float* __restrict__ x, const float* __restrict__ gw,
    const float* __restrict__ sgw, int* __restrict__ counts,
    int* __restrict__ ltok, float* __restrict__ lcoef, float* __restrict__ sg)
{
    const int wid = threadIdx.x >> 6, lane = threadIdx.x & 63;
    const int t = blockIdx.x * 4 + wid;
    const float* xr = x + (size_t)t * H_DIM;
    float xv[32];
#pragma unroll
    for (int i = 0; i < 32; ++i) xv[i] = xr[i * 64 + lane];

    float lg[E_NUM];
    for (int e = 0; e < E_NUM; ++e) {
        const float* g = gw + (size_t)e * H_DIM;
        float s = 0.f;
#pragma unroll
        for (int i = 0; i < 32; ++i) s += xv[i] * g[i * 64 + lane];
#pragma unroll
        for (int off = 32; off; off >>= 1) s += __shfl_xor(s, off);
        lg[e] = s;
    }
    {
        float s = 0.f;
#pragma unroll
        for (int i = 0; i < 32; ++i) s += xv[i] * sgw[i * 64 + lane];
#pragma unroll
        for (int off = 32; off; off >>= 1) s += __shfl_xor(s, off);
        if (lane == 0) sg[t] = 1.f / (1.f + __expf(-s));
    }
    float mx = lg[0];
#pragma unroll
    for (int e = 1; e < E_NUM; ++e) mx = fmaxf(mx, lg[e]);
    float sum = 0.f, w[E_NUM];
#pragma unroll
    for (int e = 0; e < E_NUM; ++e) { w[e] = __expf(lg[e] - mx); sum += w[e]; }
    float inv = 1.f / sum;
#pragma unroll
    for (int e = 0; e < E_NUM; ++e) w[e] *= inv;

    if (lane == 0) {
        for (int j = 0; j < TOPK; ++j) {
            float best = -1.f; int bi = 0;
            for (int e = 0; e < E_NUM; ++e) if (w[e] > best) { best = w[e]; bi = e; }
            int pos = atomicAdd(&counts[bi], 1);
            ltok[bi * M_TOK + pos]  = t;
            lcoef[bi * M_TOK + pos] = best;
            w[bi] = -2.f;
        }
    }
}

__global__ void k_prefix(const int* __restrict__ counts, int* __restrict__ base) {
    if (threadIdx.x == 0) {
        int a = 0;
        for (int e = 0; e < E_NUM; ++e) { base[e] = a; a += counts[e]; }
        base[E_NUM] = a;
    }
}

// ---------------- fp32 -> bf16 conversion (grid-stride) ----------------
__global__ __launch_bounds__(256) void k_cvtw(const float* __restrict__ src,
                                              unsigned short* __restrict__ dst, size_t n8)
{
    size_t stride = (size_t)gridDim.x * 256;
    for (size_t t = (size_t)blockIdx.x * 256 + threadIdx.x; t < n8; t += stride) {
        size_t i = t * 8;
        float4 a = *(const float4*)(src + i);
        float4 b = *(const float4*)(src + i + 4);
        union { unsigned short u[8]; short8 v; } o;
        o.u[0] = f2bf(a.x); o.u[1] = f2bf(a.y); o.u[2] = f2bf(a.z); o.u[3] = f2bf(a.w);
        o.u[4] = f2bf(b.x); o.u[5] = f2bf(b.y); o.u[6] = f2bf(b.z); o.u[7] = f2bf(b.w);
        *(short8*)(dst + i) = o.v;
    }
}

// fp32 -> bf16 with gate/up 16-row-chunk interleave within TWOI-row groups.
template<int TWOI, int NOFF>
__global__ __launch_bounds__(256) void k_cvtp(const float* __restrict__ src,
                                              unsigned short* __restrict__ dst, size_t n8)
{
    size_t stride = (size_t)gridDim.x * 256;
    for (size_t t = (size_t)blockIdx.x * 256 + threadIdx.x; t < n8; t += stride) {
        size_t i = t * 8;
        unsigned drow = (unsigned)(i >> 11);
        unsigned col  = (unsigned)(i & 2047u);
        unsigned grp = drow / (unsigned)TWOI;
        unsigned rr  = drow - grp * (unsigned)TWOI;
        unsigned q = rr >> 4, rm = rr & 15u;
        unsigned srow = ((q >> 1) << 4) + rm + ((q & 1u) ? (unsigned)NOFF : 0u);
        const float* s = src + (((size_t)grp * TWOI + srow) << 11) + col;
        float4 a = *(const float4*)s;
        float4 b = *(const float4*)(s + 4);
        union { unsigned short u[8]; short8 v; } o;
        o.u[0] = f2bf(a.x); o.u[1] = f2bf(a.y); o.u[2] = f2bf(a.z); o.u[3] = f2bf(a.w);
        o.u[4] = f2bf(b.x); o.u[5] = f2bf(b.y); o.u[6] = f2bf(b.z); o.u[7] = f2bf(b.w);
        *(short8*)(dst + i) = o.v;
    }
}

// ---------------- 256x128 3-deep-pipelined bf16 MFMA GEMM (best: R10) ----------------
// BM=256, BN=128, BK=64. 512 threads = 8 waves (4M x 2N), per-wave 64x64.
// THREE LDS buffers (144 KiB): tile t reads buf[t%3], stages t+2 into
// buf[(t+2)%3]; ONE barrier + ONE counted vmcnt(6) per K-tile (keeps this
// tile's 6 loads in flight). Tails wait vmcnt(0). Requires NT >= 2.
// K-split: MODE 1 -> z in [0,KSPLIT), kbeg=z*KCH. MODE 3 & KSPLIT>1 ->
// z = e*KSPLIT + s, kbeg = s*KCH.
template<int MODE, int KDIM, long long BSTR, int KSPLIT>
__global__ __launch_bounds__(512, 2) void k_gemm(
    const unsigned short* __restrict__ Abase,
    const unsigned short* __restrict__ Bbase,
    void* __restrict__ outp,
    const int* __restrict__ ltok, const float* __restrict__ lcoef,
    const int* __restrict__ counts, const int* __restrict__ basearr,
    const float* __restrict__ sg)
{
    constexpr bool UP = (MODE == 0 || MODE == 2);
    constexpr int OSTR = (MODE == 0) ? IS_DIM : I_DIM;   // h row stride (UP only)
    constexpr int KCH = KDIM / KSPLIT;
    constexpr int NT = KCH / 64;

    extern __shared__ unsigned short smem[];
    unsigned short* sA = smem;            // [3 buf][256 rows][64]
    unsigned short* sB = smem + 49152;    // [3 buf][128 rows][64]

    const int tid = threadIdx.x;
    const int lane = tid & 63, wid = tid >> 6;
    const int wr = wid >> 1, wc = wid & 1;       // 4M x 2N wave grid
    const int lr = lane & 15, lk = lane >> 4;

    // ---- bijective XCD-chunk swizzle over (x,y), y-major within chunk ----
    const unsigned gx = gridDim.x, gy = gridDim.y;
    const unsigned nwg = gx * gy;
    const unsigned orig = blockIdx.y * gx + blockIdx.x;
    const unsigned q8 = nwg >> 3, r8 = nwg & 7;
    const unsigned xcd = orig & 7, off8 = orig >> 3;
    const unsigned wg = ((xcd < r8) ? xcd * (q8 + 1) : r8 * (q8 + 1) + (xcd - r8) * q8) + off8;
    const int n0 = (int)(wg / gy) * 128;
    const int r0 = (int)(wg % gy) * 256;

    int e = blockIdx.z, kbeg = 0;
    if constexpr (MODE == 1) {
        kbeg = e * KCH;
    } else if constexpr (MODE == 3 && KSPLIT > 1) {
        kbeg = (e % KSPLIT) * KCH;
        e = e / KSPLIT;
    }

    int cnt = M_TOK, gbase = 0;
    if constexpr (MODE == 2 || MODE == 3) {
        cnt = counts[e];
        if (r0 >= cnt) return;
        gbase = basearr[e];
    }
    const unsigned short* Bexp = Bbase + (size_t)e * (size_t)BSTR;

    // ---- staging source pointers (pre-swizzled, fixed across K) ----
    const unsigned short* aptr[2][2];
#pragma unroll
    for (int h = 0; h < 2; ++h) {
#pragma unroll
        for (int i = 0; i < 2; ++i) {
            const int eo = (i * 512 + tid) * 8;        // elem offset in 128-row half
            const int prow = eo >> 6;                  // 0..127
            const int kch = ((eo >> 3) & 7) ^ (prow & 7);
            const int lrow = h * 128 + prow;
            int ar;
            if constexpr (MODE == 0 || MODE == 1) ar = r0 + lrow;
            else {
                int rr2 = r0 + lrow; if (rr2 > cnt - 1) rr2 = cnt - 1;
                ar = (MODE == 2) ? ltok[e * M_TOK + rr2] : (gbase + rr2);
            }
            aptr[h][i] = Abase + (size_t)ar * KDIM + kbeg + kch * 8;
        }
    }
    const unsigned short* bptr[2];
#pragma unroll
    for (int i = 0; i < 2; ++i) {
        const int eo = (i * 512 + tid) * 8;
        const int prow = eo >> 6;                      // 0..127
        const int kch = ((eo >> 3) & 7) ^ (prow & 7);
        bptr[i] = Bexp + (size_t)(n0 + prow) * KDIM + kbeg + kch * 8;
    }

    f32x4 acc[4][4];
    const f32x4 z = {0.f, 0.f, 0.f, 0.f};
#pragma unroll
    for (int m = 0; m < 4; ++m)
#pragma unroll
        for (int n = 0; n < 4; ++n) acc[m][n] = z;

    auto STAGE = [&](int buf, int kt) {
#pragma unroll
        for (int i = 0; i < 2; ++i)
            gl16(aptr[0][i] + kt, &sA[buf * 16384 + (i * 512 + tid) * 8]);
#pragma unroll
        for (int i = 0; i < 2; ++i)
            gl16(aptr[1][i] + kt, &sA[buf * 16384 + 8192 + (i * 512 + tid) * 8]);
#pragma unroll
        for (int i = 0; i < 2; ++i)
            gl16(bptr[i] + kt, &sB[buf * 8192 + (i * 512 + tid) * 8]);
    };

    // prologue: tiles 0 and 1 (12 loads); wait until tile 0's 6 done
    STAGE(0, 0);
    STAGE(1, 64);
    asm volatile("s_waitcnt vmcnt(6)" ::: "memory");
    __builtin_amdgcn_s_barrier();

    short8 af[8], bf[8];
    int rb = 0;

#pragma unroll 1
    for (int t = 0; t < NT; ++t) {
        const bool pf = (t + 2 < NT);
        int wb = rb + 2; if (wb >= 3) wb -= 3;
        const int cbA = rb * 16384, cbB = rb * 8192;

        // ---- LDS -> registers (16 x ds_read_b128) ----
#pragma unroll
        for (int m = 0; m < 4; ++m) {
            const int row = wr * 64 + m * 16 + lr;
#pragma unroll
            for (int kk = 0; kk < 2; ++kk)
                af[m * 2 + kk] = *(const short8*)&sA[cbA + (row << 6) + ((((kk << 2) + lk) ^ (row & 7)) << 3)];
        }
#pragma unroll
        for (int n = 0; n < 4; ++n) {
            const int row = wc * 64 + n * 16 + lr;
#pragma unroll
            for (int kk = 0; kk < 2; ++kk)
                bf[n * 2 + kk] = *(const short8*)&sB[cbB + (row << 6) + ((((kk << 2) + lk) ^ (row & 7)) << 3)];
        }

        // ---- issue stage of tile t+2 (2-tile prefetch distance) ----
        if (pf) STAGE(wb, (t + 2) * 64);

        // ---- 32 MFMA ----
        __builtin_amdgcn_s_setprio(1);
#pragma unroll
        for (int kk = 0; kk < 2; ++kk)
#pragma unroll
            for (int n = 0; n < 4; ++n)
#pragma unroll
                for (int m = 0; m < 4; ++m)
                    acc[m][n] = __builtin_amdgcn_mfma_f32_16x16x32_bf16(af[m * 2 + kk], bf[n * 2 + kk], acc[m][n], 0, 0, 0);
        __builtin_amdgcn_s_setprio(0);

        // ---- tile end: drain t-1's loads (buf[(t+1)%3] ready); keep t's in flight ----
        if (pf) asm volatile("s_waitcnt vmcnt(6)" ::: "memory");
        else    asm volatile("s_waitcnt vmcnt(0)" ::: "memory");
        __builtin_amdgcn_s_barrier();

        rb = (rb + 1 == 3) ? 0 : rb + 1;
    }

    // ---- epilogue ----
    if constexpr (UP) {
        const int hc0 = (n0 >> 1) + wc * 32 + lr;
        unsigned short* hb = (unsigned short*)outp;
#pragma unroll
        for (int m = 0; m < 4; ++m) {
#pragma unroll
            for (int j = 0; j < 4; ++j) {
                const int r = wr * 64 + m * 16 + lk * 4 + j;
                bool ok; size_t orow;
                if constexpr (MODE == 0) { ok = true; orow = (size_t)(r0 + r) * OSTR; }
                else { ok = (r0 + r < cnt); orow = (size_t)(gbase + r0 + r) * OSTR; }
                if (ok) {
                    float g0 = acc[m][0][j], u0 = acc[m][1][j];
                    float g1 = acc[m][2][j], u1 = acc[m][3][j];
                    hb[orow + hc0]      = f2bf(g0 / (1.f + __expf(-g0)) * u0);
                    hb[orow + hc0 + 16] = f2bf(g1 / (1.f + __expf(-g1)) * u1);
                }
            }
        }
    } else {
        float* op = (float*)outp;
#pragma unroll
        for (int m = 0; m < 4; ++m) {
#pragma unroll
            for (int j = 0; j < 4; ++j) {
                const int r = wr * 64 + m * 16 + lk * 4 + j;
                int tok; float scale; bool ok;
                if constexpr (MODE == 1) {
                    tok = r0 + r; scale = sg[tok]; ok = true;
                } else {
                    ok = (r0 + r < cnt);
                    int idx = ok ? (e * M_TOK + r0 + r) : (e * M_TOK);
                    tok = ltok[idx]; scale = lcoef[idx];
                }
                if (ok) {
                    size_t orow = (size_t)tok * H_DIM;
#pragma unroll
                    for (int n = 0; n < 4; ++n) {
                        const int col = n0 + wc * 64 + n * 16 + lr;
                        atomicAdd(op + orow + col, acc[m][n][j] * scale);
                    }
                }
            }
        }
    }
}

extern "C" void kernel_launch(void* const* d_in, const int* in_sizes, int n_in,
                              void* d_out, int out_size, void* d_ws, size_t ws_size,
                              hipStream_t stream) {
    const float* x    = (const float*)d_in[0];
    const float* gw   = (const float*)d_in[1];
    const float* sgw  = (const float*)d_in[2];
    const float* w13  = (const float*)d_in[3];
    const float* w2   = (const float*)d_in[4];
    const float* sguw = (const float*)d_in[5];
    const float* sdw  = (const float*)d_in[6];
    float* out = (float*)d_out;

    char* ws = (char*)d_ws;
    unsigned short* xb    = (unsigned short*)ws;                // 16,777,216 B
    unsigned short* hbuf  = (unsigned short*)(ws + 16777216);   // 46,137,344 B (hs then he)
    unsigned short* w13b  = (unsigned short*)(ws + 62914560);   // 184,549,376 B (permuted)
    unsigned short* w2b   = (unsigned short*)(ws + 247463936);  //  92,274,688 B
    unsigned short* sguwb = (unsigned short*)(ws + 339738624);  //  46,137,344 B (permuted)
    unsigned short* sdwb  = (unsigned short*)(ws + 385875968);  //  23,068,672 B
    size_t so = 408944640ULL;
    int*   ltok   = (int*)  (ws + so);
    float* lcoef  = (float*)(ws + so + 262144);
    int*   counts = (int*)  (ws + so + 524288);
    int*   basep  = (int*)  (ws + so + 524288 + 256);
    float* sg     = (float*)(ws + so + 524288 + 512);

    hipMemsetAsync(counts, 0, 64, stream);
    hipMemsetAsync(out, 0, (size_t)out_size * sizeof(float), stream);
    k_router<<<M_TOK / 4, 256, 0, stream>>>(x, gw, sgw, counts, ltok, lcoef, sg);
    k_prefix<<<1, 64, 0, stream>>>(counts, basep);
    k_cvtw<<<4096, 256, 0, stream>>>(x, xb, (size_t)M_TOK * H_DIM / 8);
    k_cvtp<2 * IS_DIM, IS_DIM><<<8192, 256, 0, stream>>>(sguw, sguwb, (size_t)2 * IS_DIM * H_DIM / 8);
    k_cvtw<<<8192, 256, 0, stream>>>(sdw,  sdwb,  (size_t)H_DIM * IS_DIM / 8);
    k_cvtp<2 * I_DIM, I_DIM><<<8192, 256, 0, stream>>>(w13, w13b, (size_t)E_NUM * 2 * I_DIM * H_DIM / 8);
    k_cvtw<<<8192, 256, 0, stream>>>(w2,   w2b,   (size_t)E_NUM * H_DIM * I_DIM / 8);

    static const int DYN = 147456;   // 3 x (32 KiB A + 16 KiB B)
    (void)hipFuncSetAttribute(reinterpret_cast<const void*>(&k_gemm<0, 2048, 0LL, 1>),
                              hipFuncAttributeMaxDynamicSharedMemorySize, DYN);
    (void)hipFuncSetAttribute(reinterpret_cast<const void*>(&k_gemm<1, 5632, 0LL, 4>),
                              hipFuncAttributeMaxDynamicSharedMemorySize, DYN);
    (void)hipFuncSetAttribute(reinterpret_cast<const void*>(&k_gemm<2, 2048, 5767168LL, 1>),
                              hipFuncAttributeMaxDynamicSharedMemorySize, DYN);
    (void)hipFuncSetAttribute(reinterpret_cast<const void*>(&k_gemm<3, 1408, 2883584LL, 2>),
                              hipFuncAttributeMaxDynamicSharedMemorySize, DYN);

    // shared up: xb[4096,2048] x sguwb^T -> silu-mul pairs -> hs bf16 [4096,5632]
    k_gemm<0, 2048, 0LL, 1>
        <<<dim3(2 * IS_DIM / 128, M_TOK / 256, 1), 512, DYN, stream>>>(
            xb, sguwb, hbuf, ltok, lcoef, counts, basep, sg);
    // shared down (split-K=4): hs x sdwb^T * sg -> atomicAdd out
    k_gemm<1, 5632, 0LL, 4>
        <<<dim3(H_DIM / 128, M_TOK / 256, 4), 512, DYN, stream>>>(
            hbuf, sdwb, out, ltok, lcoef, counts, basep, sg);
    // expert up (gathered): xb x w13b_e^T -> silu-mul -> he bf16 [16384,1408]
    k_gemm<2, 2048, 5767168LL, 1>
        <<<dim3(2 * I_DIM / 128, M_TOK / 256, E_NUM), 512, DYN, stream>>>(
            xb, w13b, hbuf, ltok, lcoef, counts, basep, sg);
    // expert down (split-K=2): he x w2b_e^T * coef -> atomicAdd out
    k_gemm<3, 1408, 2883584LL, 2>
        <<<dim3(H_DIM / 128, M_TOK / 256, E_NUM * 2), 512, DYN, stream>>>(
            hbuf, w2b, out, ltok, lcoef, counts, basep, sg);
}

// Round 17
// 1195.681 us; speedup vs baseline: 1.1081x; 1.1081x over previous
//
#include <hip/hip_runtime.h>
#include <hip/hip_bf16.h>

// ---- problem constants ----
#define E_NUM 16
#define TOPK 4
#define H_DIM 2048
#define I_DIM 1408
#define IS_DIM 5632
#define M_TOK 4096

typedef __attribute__((ext_vector_type(8))) short short8;
typedef __attribute__((ext_vector_type(4))) float f32x4;

static __device__ __forceinline__ unsigned short f2bf(float f) {
    unsigned int u = __float_as_uint(f);
    unsigned int r = (u + 0x7FFFu + ((u >> 16) & 1u)) >> 16;
    return (unsigned short)r;
}

static __device__ __forceinline__ void gl16(const unsigned short* g, unsigned short* l) {
    __builtin_amdgcn_global_load_lds(
        (const __attribute__((address_space(1))) unsigned int*)g,
        (__attribute__((address_space(3))) unsigned int*)l, 16, 0, 0);
}

// ---------------- router: fp32 logits, softmax, top-4, shared gate ----------------
__global__ __launch_bounds__(256) void k_router(
    const float* __restrict__ x, const float* __restrict__ gw,
    const float* __restrict__ sgw, int* __restrict__ counts,
    int* __restrict__ ltok, float* __restrict__ lcoef, float* __restrict__ sg)
{
    const int wid = threadIdx.x >> 6, lane = threadIdx.x & 63;
    const int t = blockIdx.x * 4 + wid;
    const float* xr = x + (size_t)t * H_DIM;
    float xv[32];
#pragma unroll
    for (int i = 0; i < 32; ++i) xv[i] = xr[i * 64 + lane];

    float lg[E_NUM];
    for (int e = 0; e < E_NUM; ++e) {
        const float* g = gw + (size_t)e * H_DIM;
        float s = 0.f;
#pragma unroll
        for (int i = 0; i < 32; ++i) s += xv[i] * g[i * 64 + lane];
#pragma unroll
        for (int off = 32; off; off >>= 1) s += __shfl_xor(s, off);
        lg[e] = s;
    }
    {
        float s = 0.f;
#pragma unroll
        for (int i = 0; i < 32; ++i) s += xv[i] * sgw[i * 64 + lane];
#pragma unroll
        for (int off = 32; off; off >>= 1) s += __shfl_xor(s, off);
        if (lane == 0) sg[t] = 1.f / (1.f + __expf(-s));
    }
    float mx = lg[0];
#pragma unroll
    for (int e = 1; e < E_NUM; ++e) mx = fmaxf(mx, lg[e]);
    float sum = 0.f, w[E_NUM];
#pragma unroll
    for (int e = 0; e < E_NUM; ++e) { w[e] = __expf(lg[e] - mx); sum += w[e]; }
    float inv = 1.f / sum;
#pragma unroll
    for (int e = 0; e < E_NUM; ++e) w[e] *= inv;

    if (lane == 0) {
        for (int j = 0; j < TOPK; ++j) {
            float best = -1.f; int bi = 0;
            for (int e = 0; e < E_NUM; ++e) if (w[e] > best) { best = w[e]; bi = e; }
            int pos = atomicAdd(&counts[bi], 1);
            ltok[bi * M_TOK + pos]  = t;
            lcoef[bi * M_TOK + pos] = best;
            w[bi] = -2.f;
        }
    }
}

__global__ void k_prefix(const int* __restrict__ counts, int* __restrict__ base) {
    if (threadIdx.x == 0) {
        int a = 0;
        for (int e = 0; e < E_NUM; ++e) { base[e] = a; a += counts[e]; }
        base[E_NUM] = a;
    }
}

// ---------------- fp32 -> bf16 conversion (grid-stride) ----------------
__global__ __launch_bounds__(256) void k_cvtw(const float* __restrict__ src,
                                              unsigned short* __restrict__ dst, size_t n8)
{
    size_t stride = (size_t)gridDim.x * 256;
    for (size_t t = (size_t)blockIdx.x * 256 + threadIdx.x; t < n8; t += stride) {
        size_t i = t * 8;
        float4 a = *(const float4*)(src + i);
        float4 b = *(const float4*)(src + i + 4);
        union { unsigned short u[8]; short8 v; } o;
        o.u[0] = f2bf(a.x); o.u[1] = f2bf(a.y); o.u[2] = f2bf(a.z); o.u[3] = f2bf(a.w);
        o.u[4] = f2bf(b.x); o.u[5] = f2bf(b.y); o.u[6] = f2bf(b.z); o.u[7] = f2bf(b.w);
        *(short8*)(dst + i) = o.v;
    }
}

// fp32 -> bf16 with gate/up 16-row-chunk interleave within TWOI-row groups.
template<int TWOI, int NOFF>
__global__ __launch_bounds__(256) void k_cvtp(const float* __restrict__ src,
                                              unsigned short* __restrict__ dst, size_t n8)
{
    size_t stride = (size_t)gridDim.x * 256;
    for (size_t t = (size_t)blockIdx.x * 256 + threadIdx.x; t < n8; t += stride) {
        size_t i = t * 8;
        unsigned drow = (unsigned)(i >> 11);
        unsigned col  = (unsigned)(i & 2047u);
        unsigned grp = drow / (unsigned)TWOI;
        unsigned rr  = drow - grp * (unsigned)TWOI;
        unsigned q = rr >> 4, rm = rr & 15u;
        unsigned srow = ((q >> 1) << 4) + rm + ((q & 1u) ? (unsigned)NOFF : 0u);
        const float* s = src + (((size_t)grp * TWOI + srow) << 11) + col;
        float4 a = *(const float4*)s;
        float4 b = *(const float4*)(s + 4);
        union { unsigned short u[8]; short8 v; } o;
        o.u[0] = f2bf(a.x); o.u[1] = f2bf(a.y); o.u[2] = f2bf(a.z); o.u[3] = f2bf(a.w);
        o.u[4] = f2bf(b.x); o.u[5] = f2bf(b.y); o.u[6] = f2bf(b.z); o.u[7] = f2bf(b.w);
        *(short8*)(dst + i) = o.v;
    }
}

// ---------------- 256x128 3-deep-pipelined bf16 MFMA GEMM ----------------
// BM=256, BN=128, BK=64. 512 threads = 8 waves (4M x 2N), per-wave 64x64.
// THREE LDS buffers (144 KiB): tile t reads buf[t%3], stages t+2 into
// buf[(t+2)%3]; ONE barrier + ONE counted vmcnt(6) per K-tile (keeps this
// tile's 6 loads in flight 2 tiles deep). Tails wait vmcnt(0). NT >= 2.
template<int MODE, int KDIM, long long BSTR, int KSPLIT>
__global__ __launch_bounds__(512, 2) void k_gemm(
    const unsigned short* __restrict__ Abase,
    const unsigned short* __restrict__ Bbase,
    void* __restrict__ outp,
    const int* __restrict__ ltok, const float* __restrict__ lcoef,
    const int* __restrict__ counts, const int* __restrict__ basearr,
    const float* __restrict__ sg)
{
    constexpr bool UP = (MODE == 0 || MODE == 2);
    constexpr int OSTR = (MODE == 0) ? IS_DIM : I_DIM;   // h row stride (UP only)
    constexpr int KCH = KDIM / KSPLIT;
    constexpr int NT = KCH / 64;

    extern __shared__ unsigned short smem[];
    unsigned short* sA = smem;            // [3 buf][256 rows][64]
    unsigned short* sB = smem + 49152;    // [3 buf][128 rows][64]

    const int tid = threadIdx.x;
    const int lane = tid & 63, wid = tid >> 6;
    const int wr = wid >> 1, wc = wid & 1;       // 4M x 2N wave grid
    const int lr = lane & 15, lk = lane >> 4;

    // ---- bijective XCD-chunk swizzle over (x,y), y-major within chunk ----
    const unsigned gx = gridDim.x, gy = gridDim.y;
    const unsigned nwg = gx * gy;
    const unsigned orig = blockIdx.y * gx + blockIdx.x;
    const unsigned q8 = nwg >> 3, r8 = nwg & 7;
    const unsigned xcd = orig & 7, off8 = orig >> 3;
    const unsigned wg = ((xcd < r8) ? xcd * (q8 + 1) : r8 * (q8 + 1) + (xcd - r8) * q8) + off8;
    const int n0 = (int)(wg / gy) * 128;
    const int r0 = (int)(wg % gy) * 256;
    const int e  = blockIdx.z;

    int cnt = M_TOK, gbase = 0;
    if constexpr (MODE == 2 || MODE == 3) {
        cnt = counts[e];
        if (r0 >= cnt) return;
        gbase = basearr[e];
    }
    const int kbeg = (KSPLIT > 1) ? e * KCH : 0;
    const unsigned short* Bexp = Bbase + (size_t)e * (size_t)BSTR;

    // ---- staging source pointers (pre-swizzled, fixed across K) ----
    const unsigned short* aptr[2][2];
#pragma unroll
    for (int h = 0; h < 2; ++h) {
#pragma unroll
        for (int i = 0; i < 2; ++i) {
            const int eo = (i * 512 + tid) * 8;        // elem offset in 128-row half
            const int prow = eo >> 6;                  // 0..127
            const int kch = ((eo >> 3) & 7) ^ (prow & 7);
            const int lrow = h * 128 + prow;
            int ar;
            if constexpr (MODE == 0 || MODE == 1) ar = r0 + lrow;
            else {
                int rr2 = r0 + lrow; if (rr2 > cnt - 1) rr2 = cnt - 1;
                ar = (MODE == 2) ? ltok[e * M_TOK + rr2] : (gbase + rr2);
            }
            aptr[h][i] = Abase + (size_t)ar * KDIM + kbeg + kch * 8;
        }
    }
    const unsigned short* bptr[2];
#pragma unroll
    for (int i = 0; i < 2; ++i) {
        const int eo = (i * 512 + tid) * 8;
        const int prow = eo >> 6;                      // 0..127
        const int kch = ((eo >> 3) & 7) ^ (prow & 7);
        bptr[i] = Bexp + (size_t)(n0 + prow) * KDIM + kbeg + kch * 8;
    }

    f32x4 acc[4][4];
    const f32x4 z = {0.f, 0.f, 0.f, 0.f};
#pragma unroll
    for (int m = 0; m < 4; ++m)
#pragma unroll
        for (int n = 0; n < 4; ++n) acc[m][n] = z;

    auto STAGE = [&](int buf, int kt) {
#pragma unroll
        for (int i = 0; i < 2; ++i)
            gl16(aptr[0][i] + kt, &sA[buf * 16384 + (i * 512 + tid) * 8]);
#pragma unroll
        for (int i = 0; i < 2; ++i)
            gl16(aptr[1][i] + kt, &sA[buf * 16384 + 8192 + (i * 512 + tid) * 8]);
#pragma unroll
        for (int i = 0; i < 2; ++i)
            gl16(bptr[i] + kt, &sB[buf * 8192 + (i * 512 + tid) * 8]);
    };

    // prologue: tiles 0 and 1 (12 loads); wait until tile 0's 6 done
    STAGE(0, 0);
    STAGE(1, 64);
    asm volatile("s_waitcnt vmcnt(6)" ::: "memory");
    __builtin_amdgcn_s_barrier();

    short8 af[8], bf[8];
    int rb = 0;

#pragma unroll 1
    for (int t = 0; t < NT; ++t) {
        const bool pf = (t + 2 < NT);
        int wb = rb + 2; if (wb >= 3) wb -= 3;
        const int cbA = rb * 16384, cbB = rb * 8192;

        // ---- LDS -> registers (16 x ds_read_b128) ----
#pragma unroll
        for (int m = 0; m < 4; ++m) {
            const int row = wr * 64 + m * 16 + lr;
#pragma unroll
            for (int kk = 0; kk < 2; ++kk)
                af[m * 2 + kk] = *(const short8*)&sA[cbA + (row << 6) + ((((kk << 2) + lk) ^ (row & 7)) << 3)];
        }
#pragma unroll
        for (int n = 0; n < 4; ++n) {
            const int row = wc * 64 + n * 16 + lr;
#pragma unroll
            for (int kk = 0; kk < 2; ++kk)
                bf[n * 2 + kk] = *(const short8*)&sB[cbB + (row << 6) + ((((kk << 2) + lk) ^ (row & 7)) << 3)];
        }

        // ---- issue stage of tile t+2 (2-tile prefetch distance) ----
        if (pf) STAGE(wb, (t + 2) * 64);

        // ---- 32 MFMA ----
        __builtin_amdgcn_s_setprio(1);
#pragma unroll
        for (int kk = 0; kk < 2; ++kk)
#pragma unroll
            for (int n = 0; n < 4; ++n)
#pragma unroll
                for (int m = 0; m < 4; ++m)
                    acc[m][n] = __builtin_amdgcn_mfma_f32_16x16x32_bf16(af[m * 2 + kk], bf[n * 2 + kk], acc[m][n], 0, 0, 0);
        __builtin_amdgcn_s_setprio(0);

        // ---- tile end: drain t-1's loads (buf[(t+1)%3] ready); keep t's in flight ----
        if (pf) asm volatile("s_waitcnt vmcnt(6)" ::: "memory");
        else    asm volatile("s_waitcnt vmcnt(0)" ::: "memory");
        __builtin_amdgcn_s_barrier();

        rb = (rb + 1 == 3) ? 0 : rb + 1;
    }

    // ---- epilogue ----
    if constexpr (UP) {
        const int hc0 = (n0 >> 1) + wc * 32 + lr;
        unsigned short* hb = (unsigned short*)outp;
#pragma unroll
        for (int m = 0; m < 4; ++m) {
#pragma unroll
            for (int j = 0; j < 4; ++j) {
                const int r = wr * 64 + m * 16 + lk * 4 + j;
                bool ok; size_t orow;
                if constexpr (MODE == 0) { ok = true; orow = (size_t)(r0 + r) * OSTR; }
                else { ok = (r0 + r < cnt); orow = (size_t)(gbase + r0 + r) * OSTR; }
                if (ok) {
                    float g0 = acc[m][0][j], u0 = acc[m][1][j];
                    float g1 = acc[m][2][j], u1 = acc[m][3][j];
                    hb[orow + hc0]      = f2bf(g0 / (1.f + __expf(-g0)) * u0);
                    hb[orow + hc0 + 16] = f2bf(g1 / (1.f + __expf(-g1)) * u1);
                }
            }
        }
    } else {
        float* op = (float*)outp;
#pragma unroll
        for (int m = 0; m < 4; ++m) {
#pragma unroll
            for (int j = 0; j < 4; ++j) {
                const int r = wr * 64 + m * 16 + lk * 4 + j;
                int tok; float scale; bool ok;
                if constexpr (MODE == 1) {
                    tok = r0 + r; scale = sg[tok]; ok = true;
                } else {
                    ok = (r0 + r < cnt);
                    int idx = ok ? (e * M_TOK + r0 + r) : (e * M_TOK);
                    tok = ltok[idx]; scale = lcoef[idx];
                }
                if (ok) {
                    size_t orow = (size_t)tok * H_DIM;
#pragma unroll
                    for (int n = 0; n < 4; ++n) {
                        const int col = n0 + wc * 64 + n * 16 + lr;
                        atomicAdd(op + orow + col, acc[m][n][j] * scale);
                    }
                }
            }
        }
    }
}

extern "C" void kernel_launch(void* const* d_in, const int* in_sizes, int n_in,
                              void* d_out, int out_size, void* d_ws, size_t ws_size,
                              hipStream_t stream) {
    const float* x    = (const float*)d_in[0];
    const float* gw   = (const float*)d_in[1];
    const float* sgw  = (const float*)d_in[2];
    const float* w13  = (const float*)d_in[3];
    const float* w2   = (const float*)d_in[4];
    const float* sguw = (const float*)d_in[5];
    const float* sdw  = (const float*)d_in[6];
    float* out = (float*)d_out;

    char* ws = (char*)d_ws;
    unsigned short* xb    = (unsigned short*)ws;                // 16,777,216 B
    unsigned short* hbuf  = (unsigned short*)(ws + 16777216);   // 46,137,344 B (hs then he)
    unsigned short* w13b  = (unsigned short*)(ws + 62914560);   // 184,549,376 B (permuted)
    unsigned short* w2b   = (unsigned short*)(ws + 247463936);  //  92,274,688 B
    unsigned short* sguwb = (unsigned short*)(ws + 339738624);  //  46,137,344 B (permuted)
    unsigned short* sdwb  = (unsigned short*)(ws + 385875968);  //  23,068,672 B
    size_t so = 408944640ULL;
    int*   ltok   = (int*)  (ws + so);
    float* lcoef  = (float*)(ws + so + 262144);
    int*   counts = (int*)  (ws + so + 524288);
    int*   basep  = (int*)  (ws + so + 524288 + 256);
    float* sg     = (float*)(ws + so + 524288 + 512);

    hipMemsetAsync(counts, 0, 64, stream);
    hipMemsetAsync(out, 0, (size_t)out_size * sizeof(float), stream);
    k_router<<<M_TOK / 4, 256, 0, stream>>>(x, gw, sgw, counts, ltok, lcoef, sg);
    k_prefix<<<1, 64, 0, stream>>>(counts, basep);
    k_cvtw<<<4096, 256, 0, stream>>>(x, xb, (size_t)M_TOK * H_DIM / 8);
    k_cvtp<2 * IS_DIM, IS_DIM><<<8192, 256, 0, stream>>>(sguw, sguwb, (size_t)2 * IS_DIM * H_DIM / 8);
    k_cvtw<<<8192, 256, 0, stream>>>(sdw,  sdwb,  (size_t)H_DIM * IS_DIM / 8);
    k_cvtp<2 * I_DIM, I_DIM><<<8192, 256, 0, stream>>>(w13, w13b, (size_t)E_NUM * 2 * I_DIM * H_DIM / 8);
    k_cvtw<<<8192, 256, 0, stream>>>(w2,   w2b,   (size_t)E_NUM * H_DIM * I_DIM / 8);

    static const int DYN = 147456;   // 3 x (32 KiB A + 16 KiB B)
    (void)hipFuncSetAttribute(reinterpret_cast<const void*>(&k_gemm<0, 2048, 0LL, 1>),
                              hipFuncAttributeMaxDynamicSharedMemorySize, DYN);
    (void)hipFuncSetAttribute(reinterpret_cast<const void*>(&k_gemm<1, 5632, 0LL, 2>),
                              hipFuncAttributeMaxDynamicSharedMemorySize, DYN);
    (void)hipFuncSetAttribute(reinterpret_cast<const void*>(&k_gemm<2, 2048, 5767168LL, 1>),
                              hipFuncAttributeMaxDynamicSharedMemorySize, DYN);
    (void)hipFuncSetAttribute(reinterpret_cast<const void*>(&k_gemm<3, 1408, 2883584LL, 1>),
                              hipFuncAttributeMaxDynamicSharedMemorySize, DYN);

    // shared up: xb[4096,2048] x sguwb^T -> silu-mul pairs -> hs bf16 [4096,5632]
    k_gemm<0, 2048, 0LL, 1>
        <<<dim3(2 * IS_DIM / 128, M_TOK / 256, 1), 512, DYN, stream>>>(
            xb, sguwb, hbuf, ltok, lcoef, counts, basep, sg);
    // shared down (split-K=2): hs x sdwb^T * sg -> atomicAdd out
    k_gemm<1, 5632, 0LL, 2>
        <<<dim3(H_DIM / 128, M_TOK / 256, 2), 512, DYN, stream>>>(
            hbuf, sdwb, out, ltok, lcoef, counts, basep, sg);
    // expert up (gathered): xb x w13b_e^T -> silu-mul -> he bf16 [16384,1408]
    k_gemm<2, 2048, 5767168LL, 1>
        <<<dim3(2 * I_DIM / 128, M_TOK / 256, E_NUM), 512, DYN, stream>>>(
            xb, w13b, hbuf, ltok, lcoef, counts, basep, sg);
    // expert down: he x w2b_e^T * coef -> atomicAdd out
    k_gemm<3, 1408, 2883584LL, 1>
        <<<dim3(H_DIM / 128, M_TOK / 256, E_NUM), 512, DYN, stream>>>(
            hbuf, w2b, out, ltok, lcoef, counts, basep, sg);
}

// Round 18
// 1195.598 us; speedup vs baseline: 1.1082x; 1.0001x over previous
//
#include <hip/hip_runtime.h>
#include <hip/hip_bf16.h>

// ---- problem constants ----
#define E_NUM 16
#define TOPK 4
#define H_DIM 2048
#define I_DIM 1408
#define IS_DIM 5632
#define M_TOK 4096

typedef __attribute__((ext_vector_type(8))) short short8;
typedef __attribute__((ext_vector_type(4))) float f32x4;

static __device__ __forceinline__ unsigned short f2bf(float f) {
    unsigned int u = __float_as_uint(f);
    unsigned int r = (u + 0x7FFFu + ((u >> 16) & 1u)) >> 16;
    return (unsigned short)r;
}

static __device__ __forceinline__ void gl16(const unsigned short* g, unsigned short* l) {
    __builtin_amdgcn_global_load_lds(
        (const __attribute__((address_space(1))) unsigned int*)g,
        (__attribute__((address_space(3))) unsigned int*)l, 16, 0, 0);
}

// ---------------- router: fp32 logits, softmax, top-4, shared gate ----------------
__global__ __launch_bounds__(256) void k_router(
    const float* __restrict__ x, const float* __restrict__ gw,
    const float* __restrict__ sgw, int* __restrict__ counts,
    int* __restrict__ ltok, float* __restrict__ lcoef, float* __restrict__ sg)
{
    const int wid = threadIdx.x >> 6, lane = threadIdx.x & 63;
    const int t = blockIdx.x * 4 + wid;
    const float* xr = x + (size_t)t * H_DIM;
    float xv[32];
#pragma unroll
    for (int i = 0; i < 32; ++i) xv[i] = xr[i * 64 + lane];

    float lg[E_NUM];
    for (int e = 0; e < E_NUM; ++e) {
        const float* g = gw + (size_t)e * H_DIM;
        float s = 0.f;
#pragma unroll
        for (int i = 0; i < 32; ++i) s += xv[i] * g[i * 64 + lane];
#pragma unroll
        for (int off = 32; off; off >>= 1) s += __shfl_xor(s, off);
        lg[e] = s;
    }
    {
        float s = 0.f;
#pragma unroll
        for (int i = 0; i < 32; ++i) s += xv[i] * sgw[i * 64 + lane];
#pragma unroll
        for (int off = 32; off; off >>= 1) s += __shfl_xor(s, off);
        if (lane == 0) sg[t] = 1.f / (1.f + __expf(-s));
    }
    float mx = lg[0];
#pragma unroll
    for (int e = 1; e < E_NUM; ++e) mx = fmaxf(mx, lg[e]);
    float sum = 0.f, w[E_NUM];
#pragma unroll
    for (int e = 0; e < E_NUM; ++e) { w[e] = __expf(lg[e] - mx); sum += w[e]; }
    float inv = 1.f / sum;
#pragma unroll
    for (int e = 0; e < E_NUM; ++e) w[e] *= inv;

    if (lane == 0) {
        for (int j = 0; j < TOPK; ++j) {
            float best = -1.f; int bi = 0;
            for (int e = 0; e < E_NUM; ++e) if (w[e] > best) { best = w[e]; bi = e; }
            int pos = atomicAdd(&counts[bi], 1);
            ltok[bi * M_TOK + pos]  = t;
            lcoef[bi * M_TOK + pos] = best;
            w[bi] = -2.f;
        }
    }
}

__global__ void k_prefix(const int* __restrict__ counts, int* __restrict__ base) {
    if (threadIdx.x == 0) {
        int a = 0;
        for (int e = 0; e < E_NUM; ++e) { base[e] = a; a += counts[e]; }
        base[E_NUM] = a;
    }
}

// -------- fused fp32->bf16 conversion of ALL buffers (one grid-stride pass) --------
// Segments (in 8-elem units): x | sguw(perm) | sdw | w13(perm) | w2.
// perm: gate/up 16-row-chunk interleave (chunk q even -> gate row, odd -> +NOFF).
__global__ __launch_bounds__(256) void k_cvtall(
    const float* __restrict__ x, const float* __restrict__ sguw,
    const float* __restrict__ sdw, const float* __restrict__ w13,
    const float* __restrict__ w2,
    unsigned short* __restrict__ xb, unsigned short* __restrict__ sguwb,
    unsigned short* __restrict__ sdwb, unsigned short* __restrict__ w13b,
    unsigned short* __restrict__ w2b)
{
    const size_t N0 = 1048576;    // x:    4096*2048/8
    const size_t N1 = 3932160;    // +sguw 11264*2048/8
    const size_t N2 = 5373952;    // +sdw   2048*5632/8
    const size_t N3 = 16908288;   // +w13  16*2816*2048/8
    const size_t N4 = 22675456;   // +w2   16*2048*1408/8
    size_t stride = (size_t)gridDim.x * 256;
    for (size_t t = (size_t)blockIdx.x * 256 + threadIdx.x; t < N4; t += stride) {
        const float* s; unsigned short* d;
        if (t < N0) {
            size_t i = t * 8; s = x + i; d = xb + i;
        } else if (t < N1) {
            size_t i = (t - N0) * 8;
            unsigned drow = (unsigned)(i >> 11), col = (unsigned)(i & 2047u);
            unsigned q = drow >> 4, rm = drow & 15u;
            unsigned srow = ((q >> 1) << 4) + rm + ((q & 1u) ? (unsigned)IS_DIM : 0u);
            s = sguw + ((size_t)srow << 11) + col; d = sguwb + i;
        } else if (t < N2) {
            size_t i = (t - N1) * 8; s = sdw + i; d = sdwb + i;
        } else if (t < N3) {
            size_t i = (t - N2) * 8;
            unsigned drow = (unsigned)(i >> 11), col = (unsigned)(i & 2047u);
            unsigned grp = drow / (2 * I_DIM), rr = drow - grp * (2 * I_DIM);
            unsigned q = rr >> 4, rm = rr & 15u;
            unsigned srow = ((q >> 1) << 4) + rm + ((q & 1u) ? (unsigned)I_DIM : 0u);
            s = w13 + (((size_t)grp * (2 * I_DIM) + srow) << 11) + col; d = w13b + i;
        } else {
            size_t i = (t - N3) * 8; s = w2 + i; d = w2b + i;
        }
        float4 a = *(const float4*)s;
        float4 b = *(const float4*)(s + 4);
        union { unsigned short u[8]; short8 v; } o;
        o.u[0] = f2bf(a.x); o.u[1] = f2bf(a.y); o.u[2] = f2bf(a.z); o.u[3] = f2bf(a.w);
        o.u[4] = f2bf(b.x); o.u[5] = f2bf(b.y); o.u[6] = f2bf(b.z); o.u[7] = f2bf(b.w);
        *(short8*)d = o.v;
    }
}

// ---------------- 256x128 3-deep-pipelined bf16 MFMA GEMM body ----------------
// BM=256, BN=128, BK=64. 512 threads = 8 waves (4M x 2N), per-wave 64x64.
// THREE LDS buffers (144 KiB): tile t reads buf[t%3], stages t+2 into
// buf[(t+2)%3]; ONE barrier + ONE counted vmcnt(6) per K-tile. Tails vmcnt(0).
template<int MODE, int KDIM, int KCH, long long BSTR>
__device__ __forceinline__ void gemm_body(
    const unsigned short* __restrict__ Abase,
    const unsigned short* __restrict__ Bbase,
    void* __restrict__ outp,
    const int* __restrict__ ltok, const float* __restrict__ lcoef,
    const int* __restrict__ counts, const int* __restrict__ basearr,
    const float* __restrict__ sg,
    unsigned short* smem, const int n0, const int r0, const int e, const int kbeg)
{
    constexpr bool UP = (MODE == 0 || MODE == 2);
    constexpr int OSTR = (MODE == 0) ? IS_DIM : I_DIM;   // h row stride (UP only)
    constexpr int NT = KCH / 64;

    unsigned short* sA = smem;            // [3 buf][256 rows][64]
    unsigned short* sB = smem + 49152;    // [3 buf][128 rows][64]

    const int tid = threadIdx.x;
    const int lane = tid & 63, wid = tid >> 6;
    const int wr = wid >> 1, wc = wid & 1;       // 4M x 2N wave grid
    const int lr = lane & 15, lk = lane >> 4;

    int cnt = M_TOK, gbase = 0;
    if constexpr (MODE == 2 || MODE == 3) {
        cnt = counts[e];
        if (r0 >= cnt) return;
        gbase = basearr[e];
    }
    const unsigned short* Bexp = Bbase + (size_t)e * (size_t)BSTR;

    // ---- staging source pointers (pre-swizzled, fixed across K) ----
    const unsigned short* aptr[2][2];
#pragma unroll
    for (int h = 0; h < 2; ++h) {
#pragma unroll
        for (int i = 0; i < 2; ++i) {
            const int eo = (i * 512 + tid) * 8;        // elem offset in 128-row half
            const int prow = eo >> 6;                  // 0..127
            const int kch = ((eo >> 3) & 7) ^ (prow & 7);
            const int lrow = h * 128 + prow;
            int ar;
            if constexpr (MODE == 0 || MODE == 1) ar = r0 + lrow;
            else {
                int rr2 = r0 + lrow; if (rr2 > cnt - 1) rr2 = cnt - 1;
                ar = (MODE == 2) ? ltok[e * M_TOK + rr2] : (gbase + rr2);
            }
            aptr[h][i] = Abase + (size_t)ar * KDIM + kbeg + kch * 8;
        }
    }
    const unsigned short* bptr[2];
#pragma unroll
    for (int i = 0; i < 2; ++i) {
        const int eo = (i * 512 + tid) * 8;
        const int prow = eo >> 6;                      // 0..127
        const int kch = ((eo >> 3) & 7) ^ (prow & 7);
        bptr[i] = Bexp + (size_t)(n0 + prow) * KDIM + kbeg + kch * 8;
    }

    f32x4 acc[4][4];
    const f32x4 z = {0.f, 0.f, 0.f, 0.f};
#pragma unroll
    for (int m = 0; m < 4; ++m)
#pragma unroll
        for (int n = 0; n < 4; ++n) acc[m][n] = z;

    auto STAGE = [&](int buf, int kt) {
#pragma unroll
        for (int i = 0; i < 2; ++i)
            gl16(aptr[0][i] + kt, &sA[buf * 16384 + (i * 512 + tid) * 8]);
#pragma unroll
        for (int i = 0; i < 2; ++i)
            gl16(aptr[1][i] + kt, &sA[buf * 16384 + 8192 + (i * 512 + tid) * 8]);
#pragma unroll
        for (int i = 0; i < 2; ++i)
            gl16(bptr[i] + kt, &sB[buf * 8192 + (i * 512 + tid) * 8]);
    };

    // prologue: tiles 0 and 1 (12 loads); wait until tile 0's 6 done
    STAGE(0, 0);
    STAGE(1, 64);
    asm volatile("s_waitcnt vmcnt(6)" ::: "memory");
    __builtin_amdgcn_s_barrier();

    short8 af[8], bf[8];
    int rb = 0;

#pragma unroll 1
    for (int t = 0; t < NT; ++t) {
        const bool pf = (t + 2 < NT);
        int wb = rb + 2; if (wb >= 3) wb -= 3;
        const int cbA = rb * 16384, cbB = rb * 8192;

        // ---- LDS -> registers (16 x ds_read_b128) ----
#pragma unroll
        for (int m = 0; m < 4; ++m) {
            const int row = wr * 64 + m * 16 + lr;
#pragma unroll
            for (int kk = 0; kk < 2; ++kk)
                af[m * 2 + kk] = *(const short8*)&sA[cbA + (row << 6) + ((((kk << 2) + lk) ^ (row & 7)) << 3)];
        }
#pragma unroll
        for (int n = 0; n < 4; ++n) {
            const int row = wc * 64 + n * 16 + lr;
#pragma unroll
            for (int kk = 0; kk < 2; ++kk)
                bf[n * 2 + kk] = *(const short8*)&sB[cbB + (row << 6) + ((((kk << 2) + lk) ^ (row & 7)) << 3)];
        }

        // ---- issue stage of tile t+2 (2-tile prefetch distance) ----
        if (pf) STAGE(wb, (t + 2) * 64);

        // ---- 32 MFMA ----
        __builtin_amdgcn_s_setprio(1);
#pragma unroll
        for (int kk = 0; kk < 2; ++kk)
#pragma unroll
            for (int n = 0; n < 4; ++n)
#pragma unroll
                for (int m = 0; m < 4; ++m)
                    acc[m][n] = __builtin_amdgcn_mfma_f32_16x16x32_bf16(af[m * 2 + kk], bf[n * 2 + kk], acc[m][n], 0, 0, 0);
        __builtin_amdgcn_s_setprio(0);

        // ---- tile end: drain t-1's loads; keep t's in flight ----
        if (pf) asm volatile("s_waitcnt vmcnt(6)" ::: "memory");
        else    asm volatile("s_waitcnt vmcnt(0)" ::: "memory");
        __builtin_amdgcn_s_barrier();

        rb = (rb + 1 == 3) ? 0 : rb + 1;
    }

    // ---- epilogue ----
    if constexpr (UP) {
        const int hc0 = (n0 >> 1) + wc * 32 + lr;
        unsigned short* hb = (unsigned short*)outp;
#pragma unroll
        for (int m = 0; m < 4; ++m) {
#pragma unroll
            for (int j = 0; j < 4; ++j) {
                const int r = wr * 64 + m * 16 + lk * 4 + j;
                bool ok; size_t orow;
                if constexpr (MODE == 0) { ok = true; orow = (size_t)(r0 + r) * OSTR; }
                else { ok = (r0 + r < cnt); orow = (size_t)(gbase + r0 + r) * OSTR; }
                if (ok) {
                    float g0 = acc[m][0][j], u0 = acc[m][1][j];
                    float g1 = acc[m][2][j], u1 = acc[m][3][j];
                    hb[orow + hc0]      = f2bf(g0 / (1.f + __expf(-g0)) * u0);
                    hb[orow + hc0 + 16] = f2bf(g1 / (1.f + __expf(-g1)) * u1);
                }
            }
        }
    } else {
        float* op = (float*)outp;
#pragma unroll
        for (int m = 0; m < 4; ++m) {
#pragma unroll
            for (int j = 0; j < 4; ++j) {
                const int r = wr * 64 + m * 16 + lk * 4 + j;
                int tok; float scale; bool ok;
                if constexpr (MODE == 1) {
                    tok = r0 + r; scale = sg[tok]; ok = true;
                } else {
                    ok = (r0 + r < cnt);
                    int idx = ok ? (e * M_TOK + r0 + r) : (e * M_TOK);
                    tok = ltok[idx]; scale = lcoef[idx];
                }
                if (ok) {
                    size_t orow = (size_t)tok * H_DIM;
#pragma unroll
                    for (int n = 0; n < 4; ++n) {
                        const int col = n0 + wc * 64 + n * 16 + lr;
                        atomicAdd(op + orow + col, acc[m][n][j] * scale);
                    }
                }
            }
        }
    }
}

// ---- bijective XCD-chunk swizzle over (x,y), y-major within chunk ----
static __device__ __forceinline__ void xcd_swz(int& n0, int& r0) {
    const unsigned gx = gridDim.x, gy = gridDim.y;
    const unsigned nwg = gx * gy;
    const unsigned orig = blockIdx.y * gx + blockIdx.x;
    const unsigned q8 = nwg >> 3, r8 = nwg & 7;
    const unsigned xcd = orig & 7, off8 = orig >> 3;
    const unsigned wg = ((xcd < r8) ? xcd * (q8 + 1) : r8 * (q8 + 1) + (xcd - r8) * q8) + off8;
    n0 = (int)(wg / gy) * 128;
    r0 = (int)(wg % gy) * 256;
}

// standalone up-GEMM wrapper (MODE 0 shared-up, MODE 2 expert-up)
template<int MODE, int KDIM, int KCH, long long BSTR>
__global__ __launch_bounds__(512, 2) void k_gemm(
    const unsigned short* __restrict__ Abase,
    const unsigned short* __restrict__ Bbase,
    void* __restrict__ outp,
    const int* __restrict__ ltok, const float* __restrict__ lcoef,
    const int* __restrict__ counts, const int* __restrict__ basearr,
    const float* __restrict__ sg)
{
    extern __shared__ unsigned short smem[];
    int n0, r0;
    xcd_swz(n0, r0);
    gemm_body<MODE, KDIM, KCH, BSTR>(Abase, Bbase, outp, ltok, lcoef, counts,
                                     basearr, sg, smem, n0, r0, blockIdx.z, 0);
}

// fused down-GEMM: z<2 -> shared-down split-K halves; z>=2 -> expert e=z-2
__global__ __launch_bounds__(512, 2) void k_down(
    const unsigned short* __restrict__ hs,
    const unsigned short* __restrict__ he,
    const unsigned short* __restrict__ sdwb,
    const unsigned short* __restrict__ w2b,
    float* __restrict__ out,
    const int* __restrict__ ltok, const float* __restrict__ lcoef,
    const int* __restrict__ counts, const int* __restrict__ basearr,
    const float* __restrict__ sg)
{
    extern __shared__ unsigned short smem[];
    int n0, r0;
    xcd_swz(n0, r0);
    const int z = blockIdx.z;
    if (z < 2) {
        gemm_body<1, 5632, 2816, 0LL>(hs, sdwb, out, ltok, lcoef, counts,
                                      basearr, sg, smem, n0, r0, 0, z * 2816);
    } else {
        gemm_body<3, 1408, 1408, 2883584LL>(he, w2b, out, ltok, lcoef, counts,
                                            basearr, sg, smem, n0, r0, z - 2, 0);
    }
}

extern "C" void kernel_launch(void* const* d_in, const int* in_sizes, int n_in,
                              void* d_out, int out_size, void* d_ws, size_t ws_size,
                              hipStream_t stream) {
    const float* x    = (const float*)d_in[0];
    const float* gw   = (const float*)d_in[1];
    const float* sgw  = (const float*)d_in[2];
    const float* w13  = (const float*)d_in[3];
    const float* w2   = (const float*)d_in[4];
    const float* sguw = (const float*)d_in[5];
    const float* sdw  = (const float*)d_in[6];
    float* out = (float*)d_out;

    char* ws = (char*)d_ws;
    unsigned short* xb    = (unsigned short*)ws;                // 16,777,216 B
    unsigned short* hbuf  = (unsigned short*)(ws + 16777216);   // 46,137,344 B (hs)
    unsigned short* w13b  = (unsigned short*)(ws + 62914560);   // 184,549,376 B (permuted)
    unsigned short* w2b   = (unsigned short*)(ws + 247463936);  //  92,274,688 B
    unsigned short* sguwb = (unsigned short*)(ws + 339738624);  //  46,137,344 B (permuted; dead after shared-up -> reused as he)
    unsigned short* sdwb  = (unsigned short*)(ws + 385875968);  //  23,068,672 B
    unsigned short* he    = sguwb;                              // he [16384][1408] bf16 = 46,137,344 B exact fit
    size_t so = 408944640ULL;
    int*   ltok   = (int*)  (ws + so);
    float* lcoef  = (float*)(ws + so + 262144);
    int*   counts = (int*)  (ws + so + 524288);
    int*   basep  = (int*)  (ws + so + 524288 + 256);
    float* sg     = (float*)(ws + so + 524288 + 512);

    hipMemsetAsync(counts, 0, 64, stream);
    hipMemsetAsync(out, 0, (size_t)out_size * sizeof(float), stream);
    k_router<<<M_TOK / 4, 256, 0, stream>>>(x, gw, sgw, counts, ltok, lcoef, sg);
    k_prefix<<<1, 64, 0, stream>>>(counts, basep);
    k_cvtall<<<8192, 256, 0, stream>>>(x, sguw, sdw, w13, w2,
                                       xb, sguwb, sdwb, w13b, w2b);

    static const int DYN = 147456;   // 3 x (32 KiB A + 16 KiB B)
    (void)hipFuncSetAttribute(reinterpret_cast<const void*>(&k_gemm<0, 2048, 2048, 0LL>),
                              hipFuncAttributeMaxDynamicSharedMemorySize, DYN);
    (void)hipFuncSetAttribute(reinterpret_cast<const void*>(&k_gemm<2, 2048, 2048, 5767168LL>),
                              hipFuncAttributeMaxDynamicSharedMemorySize, DYN);
    (void)hipFuncSetAttribute(reinterpret_cast<const void*>(&k_down),
                              hipFuncAttributeMaxDynamicSharedMemorySize, DYN);

    // shared up: xb[4096,2048] x sguwb^T -> silu-mul pairs -> hs bf16 [4096,5632]
    k_gemm<0, 2048, 2048, 0LL>
        <<<dim3(2 * IS_DIM / 128, M_TOK / 256, 1), 512, DYN, stream>>>(
            xb, sguwb, hbuf, ltok, lcoef, counts, basep, sg);
    // expert up (gathered): xb x w13b_e^T -> silu-mul -> he bf16 [16384,1408]
    // (writes into sguwb's region, which is dead after shared-up)
    k_gemm<2, 2048, 2048, 5767168LL>
        <<<dim3(2 * I_DIM / 128, M_TOK / 256, E_NUM), 512, DYN, stream>>>(
            xb, w13b, he, ltok, lcoef, counts, basep, sg);
    // fused downs: z<2 shared-down (split-K=2, *sg) + z>=2 expert-down (*coef)
    k_down<<<dim3(H_DIM / 128, M_TOK / 256, 2 + E_NUM), 512, DYN, stream>>>(
        hbuf, he, sdwb, w2b, out, ltok, lcoef, counts, basep, sg);
}

// Round 19
// 1146.541 us; speedup vs baseline: 1.1556x; 1.0428x over previous
//
#include <hip/hip_runtime.h>
#include <hip/hip_bf16.h>

// ---- problem constants ----
#define E_NUM 16
#define TOPK 4
#define H_DIM 2048
#define I_DIM 1408
#define IS_DIM 5632
#define M_TOK 4096

typedef __attribute__((ext_vector_type(8))) short short8;
typedef __attribute__((ext_vector_type(4))) float f32x4;

static __device__ __forceinline__ unsigned short f2bf(float f) {
    unsigned int u = __float_as_uint(f);
    unsigned int r = (u + 0x7FFFu + ((u >> 16) & 1u)) >> 16;
    return (unsigned short)r;
}

static __device__ __forceinline__ void gl16(const unsigned short* g, unsigned short* l) {
    __builtin_amdgcn_global_load_lds(
        (const __attribute__((address_space(1))) unsigned int*)g,
        (__attribute__((address_space(3))) unsigned int*)l, 16, 0, 0);
}

// ---------------- router: fp32 logits, softmax, top-4, shared gate ----------------
__global__ __launch_bounds__(256) void k_router(
    const float* __restrict__ x, const float* __restrict__ gw,
    const float* __restrict__ sgw, int* __restrict__ counts,
    int* __restrict__ ltok, float* __restrict__ lcoef, float* __restrict__ sg)
{
    const int wid = threadIdx.x >> 6, lane = threadIdx.x & 63;
    const int t = blockIdx.x * 4 + wid;
    const float* xr = x + (size_t)t * H_DIM;
    float xv[32];
#pragma unroll
    for (int i = 0; i < 32; ++i) xv[i] = xr[i * 64 + lane];

    float lg[E_NUM];
    for (int e = 0; e < E_NUM; ++e) {
        const float* g = gw + (size_t)e * H_DIM;
        float s = 0.f;
#pragma unroll
        for (int i = 0; i < 32; ++i) s += xv[i] * g[i * 64 + lane];
#pragma unroll
        for (int off = 32; off; off >>= 1) s += __shfl_xor(s, off);
        lg[e] = s;
    }
    {
        float s = 0.f;
#pragma unroll
        for (int i = 0; i < 32; ++i) s += xv[i] * sgw[i * 64 + lane];
#pragma unroll
        for (int off = 32; off; off >>= 1) s += __shfl_xor(s, off);
        if (lane == 0) sg[t] = 1.f / (1.f + __expf(-s));
    }
    float mx = lg[0];
#pragma unroll
    for (int e = 1; e < E_NUM; ++e) mx = fmaxf(mx, lg[e]);
    float sum = 0.f, w[E_NUM];
#pragma unroll
    for (int e = 0; e < E_NUM; ++e) { w[e] = __expf(lg[e] - mx); sum += w[e]; }
    float inv = 1.f / sum;
#pragma unroll
    for (int e = 0; e < E_NUM; ++e) w[e] *= inv;

    if (lane == 0) {
        for (int j = 0; j < TOPK; ++j) {
            float best = -1.f; int bi = 0;
            for (int e = 0; e < E_NUM; ++e) if (w[e] > best) { best = w[e]; bi = e; }
            int pos = atomicAdd(&counts[bi], 1);
            ltok[bi * M_TOK + pos]  = t;
            lcoef[bi * M_TOK + pos] = best;
            w[bi] = -2.f;
        }
    }
}

__global__ void k_prefix(const int* __restrict__ counts, int* __restrict__ base) {
    if (threadIdx.x == 0) {
        int a = 0;
        for (int e = 0; e < E_NUM; ++e) { base[e] = a; a += counts[e]; }
        base[E_NUM] = a;
    }
}

// -------- fused fp32->bf16 conversion of ALL buffers (one grid-stride pass) --------
__global__ __launch_bounds__(256) void k_cvtall(
    const float* __restrict__ x, const float* __restrict__ sguw,
    const float* __restrict__ sdw, const float* __restrict__ w13,
    const float* __restrict__ w2,
    unsigned short* __restrict__ xb, unsigned short* __restrict__ sguwb,
    unsigned short* __restrict__ sdwb, unsigned short* __restrict__ w13b,
    unsigned short* __restrict__ w2b)
{
    const size_t N0 = 1048576;    // x:    4096*2048/8
    const size_t N1 = 3932160;    // +sguw 11264*2048/8
    const size_t N2 = 5373952;    // +sdw   2048*5632/8
    const size_t N3 = 16908288;   // +w13  16*2816*2048/8
    const size_t N4 = 22675456;   // +w2   16*2048*1408/8
    size_t stride = (size_t)gridDim.x * 256;
    for (size_t t = (size_t)blockIdx.x * 256 + threadIdx.x; t < N4; t += stride) {
        const float* s; unsigned short* d;
        if (t < N0) {
            size_t i = t * 8; s = x + i; d = xb + i;
        } else if (t < N1) {
            size_t i = (t - N0) * 8;
            unsigned drow = (unsigned)(i >> 11), col = (unsigned)(i & 2047u);
            unsigned q = drow >> 4, rm = drow & 15u;
            unsigned srow = ((q >> 1) << 4) + rm + ((q & 1u) ? (unsigned)IS_DIM : 0u);
            s = sguw + ((size_t)srow << 11) + col; d = sguwb + i;
        } else if (t < N2) {
            size_t i = (t - N1) * 8; s = sdw + i; d = sdwb + i;
        } else if (t < N3) {
            size_t i = (t - N2) * 8;
            unsigned drow = (unsigned)(i >> 11), col = (unsigned)(i & 2047u);
            unsigned grp = drow / (2 * I_DIM), rr = drow - grp * (2 * I_DIM);
            unsigned q = rr >> 4, rm = rr & 15u;
            unsigned srow = ((q >> 1) << 4) + rm + ((q & 1u) ? (unsigned)I_DIM : 0u);
            s = w13 + (((size_t)grp * (2 * I_DIM) + srow) << 11) + col; d = w13b + i;
        } else {
            size_t i = (t - N3) * 8; s = w2 + i; d = w2b + i;
        }
        float4 a = *(const float4*)s;
        float4 b = *(const float4*)(s + 4);
        union { unsigned short u[8]; short8 v; } o;
        o.u[0] = f2bf(a.x); o.u[1] = f2bf(a.y); o.u[2] = f2bf(a.z); o.u[3] = f2bf(a.w);
        o.u[4] = f2bf(b.x); o.u[5] = f2bf(b.y); o.u[6] = f2bf(b.z); o.u[7] = f2bf(b.w);
        *(short8*)d = o.v;
    }
}

// ---------------- 256x128 3-deep-pipelined bf16 MFMA GEMM body ----------------
// MODE 1 with KCH==KDIM -> DIRECT store (covers out exactly once, no memset).
template<int MODE, int KDIM, int KCH, long long BSTR>
__device__ __forceinline__ void gemm_body(
    const unsigned short* __restrict__ Abase,
    const unsigned short* __restrict__ Bbase,
    void* __restrict__ outp,
    const int* __restrict__ ltok, const float* __restrict__ lcoef,
    const int* __restrict__ counts, const int* __restrict__ basearr,
    const float* __restrict__ sg,
    unsigned short* smem, const int n0, const int r0, const int e, const int kbeg)
{
    constexpr bool UP = (MODE == 0 || MODE == 2);
    constexpr bool DIRECT = (MODE == 1 && KCH == KDIM);
    constexpr int OSTR = (MODE == 0) ? IS_DIM : I_DIM;   // h row stride (UP only)
    constexpr int NT = KCH / 64;

    unsigned short* sA = smem;            // [3 buf][256 rows][64]
    unsigned short* sB = smem + 49152;    // [3 buf][128 rows][64]

    const int tid = threadIdx.x;
    const int lane = tid & 63, wid = tid >> 6;
    const int wr = wid >> 1, wc = wid & 1;       // 4M x 2N wave grid
    const int lr = lane & 15, lk = lane >> 4;

    int cnt = M_TOK, gbase = 0;
    if constexpr (MODE == 2 || MODE == 3) {
        cnt = counts[e];
        if (r0 >= cnt) return;
        gbase = basearr[e];
    }
    const unsigned short* Bexp = Bbase + (size_t)e * (size_t)BSTR;

    // ---- staging source pointers (pre-swizzled, fixed across K) ----
    const unsigned short* aptr[2][2];
#pragma unroll
    for (int h = 0; h < 2; ++h) {
#pragma unroll
        for (int i = 0; i < 2; ++i) {
            const int eo = (i * 512 + tid) * 8;        // elem offset in 128-row half
            const int prow = eo >> 6;                  // 0..127
            const int kch = ((eo >> 3) & 7) ^ (prow & 7);
            const int lrow = h * 128 + prow;
            int ar;
            if constexpr (MODE == 0 || MODE == 1) ar = r0 + lrow;
            else {
                int rr2 = r0 + lrow; if (rr2 > cnt - 1) rr2 = cnt - 1;
                ar = (MODE == 2) ? ltok[e * M_TOK + rr2] : (gbase + rr2);
            }
            aptr[h][i] = Abase + (size_t)ar * KDIM + kbeg + kch * 8;
        }
    }
    const unsigned short* bptr[2];
#pragma unroll
    for (int i = 0; i < 2; ++i) {
        const int eo = (i * 512 + tid) * 8;
        const int prow = eo >> 6;                      // 0..127
        const int kch = ((eo >> 3) & 7) ^ (prow & 7);
        bptr[i] = Bexp + (size_t)(n0 + prow) * KDIM + kbeg + kch * 8;
    }

    f32x4 acc[4][4];
    const f32x4 z = {0.f, 0.f, 0.f, 0.f};
#pragma unroll
    for (int m = 0; m < 4; ++m)
#pragma unroll
        for (int n = 0; n < 4; ++n) acc[m][n] = z;

    auto STAGE = [&](int buf, int kt) {
#pragma unroll
        for (int i = 0; i < 2; ++i)
            gl16(aptr[0][i] + kt, &sA[buf * 16384 + (i * 512 + tid) * 8]);
#pragma unroll
        for (int i = 0; i < 2; ++i)
            gl16(aptr[1][i] + kt, &sA[buf * 16384 + 8192 + (i * 512 + tid) * 8]);
#pragma unroll
        for (int i = 0; i < 2; ++i)
            gl16(bptr[i] + kt, &sB[buf * 8192 + (i * 512 + tid) * 8]);
    };

    // prologue: tiles 0 and 1 (12 loads); wait until tile 0's 6 done
    STAGE(0, 0);
    STAGE(1, 64);
    asm volatile("s_waitcnt vmcnt(6)" ::: "memory");
    __builtin_amdgcn_s_barrier();

    short8 af[8], bf[8];
    int rb = 0;

#pragma unroll 1
    for (int t = 0; t < NT; ++t) {
        const bool pf = (t + 2 < NT);
        int wb = rb + 2; if (wb >= 3) wb -= 3;
        const int cbA = rb * 16384, cbB = rb * 8192;

        // ---- LDS -> registers (16 x ds_read_b128) ----
#pragma unroll
        for (int m = 0; m < 4; ++m) {
            const int row = wr * 64 + m * 16 + lr;
#pragma unroll
            for (int kk = 0; kk < 2; ++kk)
                af[m * 2 + kk] = *(const short8*)&sA[cbA + (row << 6) + ((((kk << 2) + lk) ^ (row & 7)) << 3)];
        }
#pragma unroll
        for (int n = 0; n < 4; ++n) {
            const int row = wc * 64 + n * 16 + lr;
#pragma unroll
            for (int kk = 0; kk < 2; ++kk)
                bf[n * 2 + kk] = *(const short8*)&sB[cbB + (row << 6) + ((((kk << 2) + lk) ^ (row & 7)) << 3)];
        }

        // ---- issue stage of tile t+2 (2-tile prefetch distance) ----
        if (pf) STAGE(wb, (t + 2) * 64);

        // ---- 32 MFMA ----
        __builtin_amdgcn_s_setprio(1);
#pragma unroll
        for (int kk = 0; kk < 2; ++kk)
#pragma unroll
            for (int n = 0; n < 4; ++n)
#pragma unroll
                for (int m = 0; m < 4; ++m)
                    acc[m][n] = __builtin_amdgcn_mfma_f32_16x16x32_bf16(af[m * 2 + kk], bf[n * 2 + kk], acc[m][n], 0, 0, 0);
        __builtin_amdgcn_s_setprio(0);

        // ---- tile end: drain t-1's loads; keep t's in flight ----
        if (pf) asm volatile("s_waitcnt vmcnt(6)" ::: "memory");
        else    asm volatile("s_waitcnt vmcnt(0)" ::: "memory");
        __builtin_amdgcn_s_barrier();

        rb = (rb + 1 == 3) ? 0 : rb + 1;
    }

    // ---- epilogue ----
    if constexpr (UP) {
        const int hc0 = (n0 >> 1) + wc * 32 + lr;
        unsigned short* hb = (unsigned short*)outp;
#pragma unroll
        for (int m = 0; m < 4; ++m) {
#pragma unroll
            for (int j = 0; j < 4; ++j) {
                const int r = wr * 64 + m * 16 + lk * 4 + j;
                bool ok; size_t orow;
                if constexpr (MODE == 0) { ok = true; orow = (size_t)(r0 + r) * OSTR; }
                else { ok = (r0 + r < cnt); orow = (size_t)(gbase + r0 + r) * OSTR; }
                if (ok) {
                    float g0 = acc[m][0][j], u0 = acc[m][1][j];
                    float g1 = acc[m][2][j], u1 = acc[m][3][j];
                    hb[orow + hc0]      = f2bf(g0 / (1.f + __expf(-g0)) * u0);
                    hb[orow + hc0 + 16] = f2bf(g1 / (1.f + __expf(-g1)) * u1);
                }
            }
        }
    } else {
        float* op = (float*)outp;
#pragma unroll
        for (int m = 0; m < 4; ++m) {
#pragma unroll
            for (int j = 0; j < 4; ++j) {
                const int r = wr * 64 + m * 16 + lk * 4 + j;
                int tok; float scale; bool ok;
                if constexpr (MODE == 1) {
                    tok = r0 + r; scale = sg[tok]; ok = true;
                } else {
                    ok = (r0 + r < cnt);
                    int idx = ok ? (e * M_TOK + r0 + r) : (e * M_TOK);
                    tok = ltok[idx]; scale = lcoef[idx];
                }
                if (ok) {
                    size_t orow = (size_t)tok * H_DIM;
#pragma unroll
                    for (int n = 0; n < 4; ++n) {
                        const int col = n0 + wc * 64 + n * 16 + lr;
                        if constexpr (DIRECT)
                            op[orow + col] = acc[m][n][j] * scale;   // first+only full pass
                        else
                            atomicAdd(op + orow + col, acc[m][n][j] * scale);
                    }
                }
            }
        }
    }
}

// ---- bijective XCD-chunk swizzle over (x,y), y-major within chunk ----
static __device__ __forceinline__ void xcd_swz(int& n0, int& r0) {
    const unsigned gx = gridDim.x, gy = gridDim.y;
    const unsigned nwg = gx * gy;
    const unsigned orig = blockIdx.y * gx + blockIdx.x;
    const unsigned q8 = nwg >> 3, r8 = nwg & 7;
    const unsigned xcd = orig & 7, off8 = orig >> 3;
    const unsigned wg = ((xcd < r8) ? xcd * (q8 + 1) : r8 * (q8 + 1) + (xcd - r8) * q8) + off8;
    n0 = (int)(wg / gy) * 128;
    r0 = (int)(wg % gy) * 256;
}

template<int MODE, int KDIM, int KCH, long long BSTR>
__global__ __launch_bounds__(512, 2) void k_gemm(
    const unsigned short* __restrict__ Abase,
    const unsigned short* __restrict__ Bbase,
    void* __restrict__ outp,
    const int* __restrict__ ltok, const float* __restrict__ lcoef,
    const int* __restrict__ counts, const int* __restrict__ basearr,
    const float* __restrict__ sg)
{
    extern __shared__ unsigned short smem[];
    int n0, r0;
    xcd_swz(n0, r0);
    gemm_body<MODE, KDIM, KCH, BSTR>(Abase, Bbase, outp, ltok, lcoef, counts,
                                     basearr, sg, smem, n0, r0, blockIdx.z, 0);
}

extern "C" void kernel_launch(void* const* d_in, const int* in_sizes, int n_in,
                              void* d_out, int out_size, void* d_ws, size_t ws_size,
                              hipStream_t stream) {
    const float* x    = (const float*)d_in[0];
    const float* gw   = (const float*)d_in[1];
    const float* sgw  = (const float*)d_in[2];
    const float* w13  = (const float*)d_in[3];
    const float* w2   = (const float*)d_in[4];
    const float* sguw = (const float*)d_in[5];
    const float* sdw  = (const float*)d_in[6];
    float* out = (float*)d_out;

    char* ws = (char*)d_ws;
    unsigned short* xb    = (unsigned short*)ws;                // 16,777,216 B
    unsigned short* hbuf  = (unsigned short*)(ws + 16777216);   // 46,137,344 B (hs)
    unsigned short* w13b  = (unsigned short*)(ws + 62914560);   // 184,549,376 B (permuted)
    unsigned short* w2b   = (unsigned short*)(ws + 247463936);  //  92,274,688 B
    unsigned short* sguwb = (unsigned short*)(ws + 339738624);  //  46,137,344 B (permuted; dead after shared-up -> reused as he)
    unsigned short* sdwb  = (unsigned short*)(ws + 385875968);  //  23,068,672 B
    unsigned short* he    = sguwb;                              // he [16384][1408] bf16, exact fit
    size_t so = 408944640ULL;
    int*   ltok   = (int*)  (ws + so);
    float* lcoef  = (float*)(ws + so + 262144);
    int*   counts = (int*)  (ws + so + 524288);
    int*   basep  = (int*)  (ws + so + 524288 + 256);
    float* sg     = (float*)(ws + so + 524288 + 512);

    hipMemsetAsync(counts, 0, 64, stream);
    k_router<<<M_TOK / 4, 256, 0, stream>>>(x, gw, sgw, counts, ltok, lcoef, sg);
    k_prefix<<<1, 64, 0, stream>>>(counts, basep);
    k_cvtall<<<8192, 256, 0, stream>>>(x, sguw, sdw, w13, w2,
                                       xb, sguwb, sdwb, w13b, w2b);

    static const int DYN = 147456;   // 3 x (32 KiB A + 16 KiB B)
    (void)hipFuncSetAttribute(reinterpret_cast<const void*>(&k_gemm<0, 2048, 2048, 0LL>),
                              hipFuncAttributeMaxDynamicSharedMemorySize, DYN);
    (void)hipFuncSetAttribute(reinterpret_cast<const void*>(&k_gemm<2, 2048, 2048, 5767168LL>),
                              hipFuncAttributeMaxDynamicSharedMemorySize, DYN);
    (void)hipFuncSetAttribute(reinterpret_cast<const void*>(&k_gemm<1, 5632, 5632, 0LL>),
                              hipFuncAttributeMaxDynamicSharedMemorySize, DYN);
    (void)hipFuncSetAttribute(reinterpret_cast<const void*>(&k_gemm<3, 1408, 1408, 2883584LL>),
                              hipFuncAttributeMaxDynamicSharedMemorySize, DYN);

    // shared up: xb x sguwb^T -> silu-mul pairs -> hs bf16 [4096,5632]
    k_gemm<0, 2048, 2048, 0LL>
        <<<dim3(2 * IS_DIM / 128, M_TOK / 256, 1), 512, DYN, stream>>>(
            xb, sguwb, hbuf, ltok, lcoef, counts, basep, sg);
    // expert up (gathered): xb x w13b_e^T -> silu-mul -> he bf16 [16384,1408]
    k_gemm<2, 2048, 2048, 5767168LL>
        <<<dim3(2 * I_DIM / 128, M_TOK / 256, E_NUM), 512, DYN, stream>>>(
            xb, w13b, he, ltok, lcoef, counts, basep, sg);
    // shared down (unsplit, DIRECT store -> initializes out, no memset):
    k_gemm<1, 5632, 5632, 0LL>
        <<<dim3(H_DIM / 128, M_TOK / 256, 1), 512, DYN, stream>>>(
            hbuf, sdwb, out, ltok, lcoef, counts, basep, sg);
    // expert down: he x w2b_e^T * coef -> atomicAdd out (after direct store)
    k_gemm<3, 1408, 1408, 2883584LL>
        <<<dim3(H_DIM / 128, M_TOK / 256, E_NUM), 512, DYN, stream>>>(
            he, w2b, out, ltok, lcoef, counts, basep, sg);
}